// Round 4
// baseline (534.475 us; speedup 1.0000x reference)
//
#include <hip/hip_runtime.h>
#include <hip/hip_bf16.h>

// Top2Router: T=16384 tokens, D=4096, E=64 experts.
// logits = x @ W^T + b ; probs = softmax(logits); top2; gating = scatter(softmax(top2_probs))
//
// Design:
//  - logits via split-bf16 MFMA (hi*hi + hi*lo + lo*hi), K-split-4 atomicAdd into d_out
//  - finalize: wave(64 lanes)-per-token, lane==expert; softmax + top-3 argmax; write gating
//  - rows whose (2nd - 3rd) logit gap < TAU are recomputed exactly in fp32 (flip-proof)
//  - safety net: if ws_size is too small for Whi/Wlo, run exact fp32 wave-per-token path

typedef float  f32x4 __attribute__((ext_vector_type(4)));
typedef short  s16x8 __attribute__((ext_vector_type(8)));   // 8 bf16 = 4 VGPRs (MFMA A/B frag)
typedef short  s16x4 __attribute__((ext_vector_type(4)));

#define T_TOK   16384
#define D_DIM   4096
#define E_EXP   64
#define KSPLIT  4
#define TAU     0.004f   // logit-gap threshold for exact-recompute fallback (~200 sigma of bf16x3 error)
#define WS_NEED (1024 * 1024 + 4 + 4 * T_TOK)

// ---------------- bf16 helpers ----------------
__device__ __forceinline__ unsigned short f2bf_rn(float f) {
    unsigned u = __builtin_bit_cast(unsigned, f);
    unsigned r = u + 0x7fffu + ((u >> 16) & 1u);   // round-to-nearest-even (finite inputs)
    return (unsigned short)(r >> 16);
}

// ---------------- kernel 1: one-time W -> (W_hi, W_lo) bf16 split ----------------
__global__ __launch_bounds__(256)
void convw_kernel(const float* __restrict__ W, short* __restrict__ Whi, short* __restrict__ Wlo) {
    const int i = (blockIdx.x * 256 + threadIdx.x) * 4;   // 262144 elements total, grid=256
    f32x4 v = *(const f32x4*)(W + i);
    s16x4 h, l;
#pragma unroll
    for (int j = 0; j < 4; ++j) {
        unsigned short hb = f2bf_rn(v[j]);
        h[j] = (short)hb;
        float hf = __builtin_bit_cast(float, (unsigned)hb << 16);
        l[j] = (short)f2bf_rn(v[j] - hf);
    }
    *(s16x4*)(Whi + i) = h;
    *(s16x4*)(Wlo + i) = l;
}

// ---------------- kernel 2: logits GEMM (split-bf16 MFMA, K-split atomic accumulate) ----
// grid = (T/64, KSPLIT), block = 256 (4 waves). Wave w owns tokens [blk*64 + w*16, +16) x all 64 experts.
// A frag (16x32 of x): lane l -> row l&15, k = (l>>4)*8 + j  (contiguous-8 k-slice, m91/m92 pattern)
// B frag (32x16 of W^T): lane l -> expert n*16 + (l&15), same k slice (8 consecutive bf16 from W row)
// C/D:  col = lane&15 (expert), row = (lane>>4)*4 + reg  (m89-verified mapping)
__global__ __launch_bounds__(256, 4)
void gemm_logits(const float* __restrict__ x, const short* __restrict__ Whi,
                 const short* __restrict__ Wlo, float* __restrict__ out) {
    const int lane = threadIdx.x & 63;
    const int wid  = threadIdx.x >> 6;
    const int r16  = lane & 15;
    const int kb8  = (lane >> 4) << 3;               // 0,8,16,24
    const int trow = blockIdx.x * 64 + wid * 16 + r16;
    const int kbase = blockIdx.y * (D_DIM / KSPLIT); // 1024-wide K slice

    const float* ax = x   + (long)trow * D_DIM + kbase + kb8;
    const short* bh = Whi + (long)r16  * D_DIM + kbase + kb8;
    const short* bl = Wlo + (long)r16  * D_DIM + kbase + kb8;

    f32x4 acc[4];
#pragma unroll
    for (int n = 0; n < 4; ++n) acc[n] = (f32x4){0.f, 0.f, 0.f, 0.f};

    for (int ks = 0; ks < D_DIM / KSPLIT; ks += 32) {
        // ---- A: 8 fp32 -> hi/lo bf16 (truncation split: hi = top 16 bits; lo = RN(f - hi)) ----
        f32x4 a0 = *(const f32x4*)(ax + ks);
        f32x4 a1 = *(const f32x4*)(ax + ks + 4);
        s16x8 ahi, alo;
#pragma unroll
        for (int j = 0; j < 8; ++j) {
            float f = (j < 4) ? a0[j] : a1[j - 4];
            unsigned u = __builtin_bit_cast(unsigned, f);
            float hf = __builtin_bit_cast(float, u & 0xffff0000u);
            ahi[j] = (short)(u >> 16);
            alo[j] = (short)(__builtin_bit_cast(unsigned, f - hf) >> 16);
        }
        // ---- B tiles + 3 MFMAs each (hi*hi + lo*hi + hi*lo) ----
#pragma unroll
        for (int n = 0; n < 4; ++n) {
            s16x8 bhi = *(const s16x8*)(bh + (long)n * 16 * D_DIM + ks);
            s16x8 blo = *(const s16x8*)(bl + (long)n * 16 * D_DIM + ks);
            acc[n] = __builtin_amdgcn_mfma_f32_16x16x32_bf16(ahi, bhi, acc[n], 0, 0, 0);
            acc[n] = __builtin_amdgcn_mfma_f32_16x16x32_bf16(alo, bhi, acc[n], 0, 0, 0);
            acc[n] = __builtin_amdgcn_mfma_f32_16x16x32_bf16(ahi, blo, acc[n], 0, 0, 0);
        }
    }

    const int orow = blockIdx.x * 64 + wid * 16 + ((lane >> 4) << 2);
#pragma unroll
    for (int n = 0; n < 4; ++n)
#pragma unroll
        for (int r = 0; r < 4; ++r)
            atomicAdd(out + (long)(orow + r) * E_EXP + n * 16 + r16, acc[n][r]);
}

// ---------------- per-wave gating: softmax + top2 + scatter; returns (2nd - 3rd) gap ----
__device__ __forceinline__ void argmax64(float& v, int& i) {
#pragma unroll
    for (int s = 32; s > 0; s >>= 1) {
        float ov = __shfl_xor(v, s);
        int   oi = __shfl_xor(i, s);
        if (ov > v || (ov == v && oi < i)) { v = ov; i = oi; }   // tie-break: lower index (top_k)
    }
}

__device__ __forceinline__ float wave_gate_write(float l, int lane, float* __restrict__ outrow) {
    float v1 = l; int i1 = lane; argmax64(v1, i1);
    float v2 = (lane == i1) ? -INFINITY : l; int i2 = lane; argmax64(v2, i2);
    float v3 = (lane == i1 || lane == i2) ? -INFINITY : l; int i3 = lane; argmax64(v3, i3);
    (void)i3;

    float ex = __expf(l - v1);             // max = v1
    float Z = ex;
#pragma unroll
    for (int s = 32; s > 0; s >>= 1) Z += __shfl_xor(Z, s);

    float p1 = 1.0f / Z;                   // exp(v1-v1)/Z  (top-1 probability)
    float p2 = __expf(v2 - v1) / Z;        // top-2 probability
    float g1 = 1.0f / (1.0f + __expf(p2 - p1));   // softmax over [p1,p2] -- probs, per reference
    float g2 = 1.0f / (1.0f + __expf(p1 - p2));

    outrow[lane] = (lane == i1) ? g1 : (lane == i2) ? g2 : 0.0f;
    return v2 - v3;
}

// ---------------- kernel 3: finalize (logits -> gating in-place) + flag risky rows ------
__global__ __launch_bounds__(256)
void finalize_router(float* __restrict__ out, const float* __restrict__ b,
                     int* __restrict__ flagc, int* __restrict__ flaglist) {
    const int lane = threadIdx.x & 63;
    const int t = blockIdx.x * 4 + (threadIdx.x >> 6);
    float l = out[(long)t * E_EXP + lane] + b[lane];
    float gap = wave_gate_write(l, lane, out + (long)t * E_EXP);
    if (gap < TAU && lane == 0) {
        int pos = atomicAdd(flagc, 1);
        flaglist[pos] = t;
    }
}

// ---------------- exact fp32 row compute (shared by fallback + no-ws path) --------------
__device__ __forceinline__ void exact_row(const float* __restrict__ x, const float* __restrict__ W,
                                          const float* __restrict__ b, float* __restrict__ out,
                                          int t, int lane, int w, float (*lds)[64]) {
    const float* xr = x + (long)t * D_DIM + w * 1024;    // broadcast across lanes (L1)
    const float* wr = W + (long)lane * D_DIM + w * 1024; // lane = expert
    float acc = 0.f;
    for (int k = 0; k < 1024; k += 4) {
        f32x4 xv = *(const f32x4*)(xr + k);
        f32x4 wv = *(const f32x4*)(wr + k);
        acc += xv[0]*wv[0] + xv[1]*wv[1] + xv[2]*wv[2] + xv[3]*wv[3];
    }
    lds[w][lane] = acc;
    __syncthreads();
    if (w == 0) {
        float l = lds[0][lane] + lds[1][lane] + lds[2][lane] + lds[3][lane] + b[lane];
        wave_gate_write(l, lane, out + (long)t * E_EXP);
    }
    __syncthreads();
}

// ---------------- kernel 4: exact fp32 recompute for flagged rows -----------------------
__global__ __launch_bounds__(256)
void fallback_exact(const float* __restrict__ x, const float* __restrict__ W,
                    const float* __restrict__ b, float* __restrict__ out,
                    const int* __restrict__ flags) {
    const int count = flags[0];
    const int lane = threadIdx.x & 63;
    const int w = threadIdx.x >> 6;
    __shared__ float lds[4][64];
    for (int fi = blockIdx.x; fi < count; fi += gridDim.x)
        exact_row(x, W, b, out, flags[1 + fi], lane, w, lds);
}

// ---------------- no-workspace safety net: exact fp32 for ALL rows ----------------------
__global__ __launch_bounds__(256)
void exact_all(const float* __restrict__ x, const float* __restrict__ W,
               const float* __restrict__ b, float* __restrict__ out) {
    const int lane = threadIdx.x & 63;
    const int w = threadIdx.x >> 6;
    __shared__ float lds[4][64];
    for (int t = blockIdx.x; t < T_TOK; t += gridDim.x)
        exact_row(x, W, b, out, t, lane, w, lds);
}

// ---------------- launch ----------------------------------------------------------------
extern "C" void kernel_launch(void* const* d_in, const int* in_sizes, int n_in,
                              void* d_out, int out_size, void* d_ws, size_t ws_size,
                              hipStream_t stream) {
    const float* x = (const float*)d_in[0];
    const float* W = (const float*)d_in[1];
    const float* b = (const float*)d_in[2];
    float* out = (float*)d_out;

    if (ws_size < (size_t)WS_NEED) {           // constant per-session -> graph-safe
        exact_all<<<2048, 256, 0, stream>>>(x, W, b, out);
        return;
    }

    char* ws = (char*)d_ws;
    short* Whi = (short*)ws;                          // 512 KiB
    short* Wlo = (short*)(ws + 512 * 1024);           // 512 KiB
    int* flagc    = (int*)(ws + 1024 * 1024);         // 4 B counter
    int* flaglist = flagc + 1;                        // up to 16384 ints (64 KiB)

    hipMemsetAsync(out, 0, (size_t)T_TOK * E_EXP * sizeof(float), stream);  // logit accumulator
    hipMemsetAsync(flagc, 0, sizeof(int), stream);

    convw_kernel<<<256, 256, 0, stream>>>(W, Whi, Wlo);
    gemm_logits<<<dim3(T_TOK / 64, KSPLIT), 256, 0, stream>>>(x, Whi, Wlo, out);
    finalize_router<<<T_TOK / 4, 256, 0, stream>>>(out, b, flagc, flaglist);
    fallback_exact<<<256, 256, 0, stream>>>(x, W, b, out, flagc);
}

// Round 6
// 477.727 us; speedup vs baseline: 1.1188x; 1.1188x over previous
//
#include <hip/hip_runtime.h>
#include <hip/hip_bf16.h>

// Top2Router: T=16384 tokens, D=4096, E=64 experts.
// logits = x @ W^T + b ; probs = softmax(logits); top2; gating = scatter(softmax(top2_probs))
//
// R5 design (resubmit after acquisition timeout):
//  - gemm: 256-token blocks (4 waves x 64 tokens), KSPLIT=8, W hi/lo staged in LDS
//    (global_load_lds w=16, double-buffered, XOR-swizzled src+read), split-bf16 MFMA
//  - finalize: wave-per-token softmax/top2/scatter; risky rows (gap<TAU) recomputed fp32
//  - safety net path if ws too small

typedef float  f32x4 __attribute__((ext_vector_type(4)));
typedef short  s16x8 __attribute__((ext_vector_type(8)));   // 8 bf16 = 4 VGPRs (MFMA A/B frag)
typedef short  s16x4 __attribute__((ext_vector_type(4)));
typedef unsigned int u32;

#define T_TOK   16384
#define D_DIM   4096
#define E_EXP   64
#define KSPLIT  8
#define KSLICE  (D_DIM / KSPLIT)   // 512
#define KCHUNK  128
#define NCHUNK  (KSLICE / KCHUNK)  // 4
#define TAU     0.004f   // logit-gap threshold for exact-recompute fallback (~130 sigma of bf16x3 error)
#define WS_NEED (1024 * 1024 + 4 + 4 * T_TOK)

// ---------------- bf16 helpers ----------------
__device__ __forceinline__ unsigned short f2bf_rn(float f) {
    unsigned u = __builtin_bit_cast(unsigned, f);
    unsigned r = u + 0x7fffu + ((u >> 16) & 1u);   // round-to-nearest-even (finite inputs)
    return (unsigned short)(r >> 16);
}

__device__ __forceinline__ void gl16(const void* g, void* l) {
    // async global->LDS, 16B/lane; LDS dest = wave-uniform base + lane*16 (m104)
    __builtin_amdgcn_global_load_lds((const __attribute__((address_space(1))) u32*)g,
                                     (__attribute__((address_space(3))) u32*)l, 16, 0, 0);
}

// ---------------- kernel 1: one-time W -> (W_hi, W_lo) bf16 split ----------------
__global__ __launch_bounds__(256)
void convw_kernel(const float* __restrict__ W, short* __restrict__ Whi, short* __restrict__ Wlo) {
    const int i = (blockIdx.x * 256 + threadIdx.x) * 4;   // 262144 elements total, grid=256
    f32x4 v = *(const f32x4*)(W + i);
    s16x4 h, l;
#pragma unroll
    for (int j = 0; j < 4; ++j) {
        unsigned short hb = f2bf_rn(v[j]);
        h[j] = (short)hb;
        float hf = __builtin_bit_cast(float, (unsigned)hb << 16);
        l[j] = (short)f2bf_rn(v[j] - hf);
    }
    *(s16x4*)(Whi + i) = h;
    *(s16x4*)(Wlo + i) = l;
}

// ---------------- kernel 2: logits GEMM -------------------------------------------------
// grid = (T/256, KSPLIT), block = 256 (4 waves, 64 tokens each). All 64 experts per block.
// LDS: [2 buf][hi/lo][64 experts][128 k] bf16 = 64 KiB, double-buffered K-chunks.
// Swizzle: byte-in-row c -> c ^ ((expert&7)<<4), applied on global SRC at stage and on read.
// A frag: row=lane&15, k=(lane>>4)*8+j ; B frag: col=n*16+(lane&15), same k slice
// C/D: col=lane&15 (expert), row=(lane>>4)*4+reg (m89)
__global__ __launch_bounds__(256, 2)
void gemm_logits(const float* __restrict__ x, const short* __restrict__ Whi,
                 const short* __restrict__ Wlo, float* __restrict__ out) {
    __shared__ __align__(16) short ldsb[2][2][64 * 128];   // 64 KiB
    const int lane = threadIdx.x & 63;
    const int wid  = threadIdx.x >> 6;
    const int r16  = lane & 15;
    const int q16  = lane >> 4;
    const int tb   = blockIdx.x * 256 + wid * 64;
    const int kbase = blockIdx.y * KSLICE;

    const float* ax[4];
#pragma unroll
    for (int m = 0; m < 4; ++m)
        ax[m] = x + (long)(tb + m * 16 + r16) * D_DIM + kbase + q16 * 8;

    f32x4 acc[4][4];
#pragma unroll
    for (int m = 0; m < 4; ++m)
#pragma unroll
        for (int n = 0; n < 4; ++n) acc[m][n] = (f32x4){0.f, 0.f, 0.f, 0.f};

    // ---- staging: chunk c (128 k) of both hi and lo into buf bb ----
#define STAGE(c_, bb_)                                                              \
    {                                                                               \
        _Pragma("unroll")                                                           \
        for (int r = 0; r < 4; ++r) {                                               \
            const int o  = wid * 4096 + r * 1024 + lane * 16; /* byte in 16KiB */   \
            const int e  = o >> 8;                                                  \
            const int cs = (o & 255) ^ ((e & 7) << 4);        /* inverse swizzle */ \
            const long gb = (long)e * (D_DIM * 2) + (long)(kbase + (c_)*KCHUNK) * 2 + cs; \
            const int lb = wid * 4096 + r * 1024;                                   \
            gl16((const char*)Whi + gb, (char*)&ldsb[bb_][0][0] + lb);              \
            gl16((const char*)Wlo + gb, (char*)&ldsb[bb_][1][0] + lb);              \
        }                                                                           \
    }

    STAGE(0, 0);
    __syncthreads();

#pragma unroll
    for (int c = 0; c < NCHUNK; ++c) {
        const int buf = c & 1;
        if (c + 1 < NCHUNK) STAGE(c + 1, buf ^ 1);

#pragma unroll
        for (int s = 0; s < 4; ++s) {
            const int ko = c * KCHUNK + s * 32;
            // A: load + hi/lo split, 4 m-frags
            s16x8 ahi[4], alo[4];
#pragma unroll
            for (int m = 0; m < 4; ++m) {
                f32x4 a0 = *(const f32x4*)(ax[m] + ko);
                f32x4 a1 = *(const f32x4*)(ax[m] + ko + 4);
#pragma unroll
                for (int j = 0; j < 8; ++j) {
                    float f = (j < 4) ? a0[j] : a1[j - 4];
                    u32 u = __builtin_bit_cast(u32, f);
                    float hf = __builtin_bit_cast(float, u & 0xffff0000u);
                    ahi[m][j] = (short)(u >> 16);
                    alo[m][j] = (short)(__builtin_bit_cast(u32, f - hf) >> 16);
                }
            }
            const int crow = s * 64 + q16 * 16;   // byte col within 256B expert row
#pragma unroll
            for (int n = 0; n < 4; ++n) {
                const int e   = n * 16 + r16;
                const int off = e * 256 + (crow ^ ((e & 7) << 4));
                s16x8 bhi = *(const s16x8*)((const char*)&ldsb[buf][0][0] + off);
                s16x8 blo = *(const s16x8*)((const char*)&ldsb[buf][1][0] + off);
#pragma unroll
                for (int m = 0; m < 4; ++m) {
                    acc[m][n] = __builtin_amdgcn_mfma_f32_16x16x32_bf16(ahi[m], bhi, acc[m][n], 0, 0, 0);
                    acc[m][n] = __builtin_amdgcn_mfma_f32_16x16x32_bf16(alo[m], bhi, acc[m][n], 0, 0, 0);
                    acc[m][n] = __builtin_amdgcn_mfma_f32_16x16x32_bf16(ahi[m], blo, acc[m][n], 0, 0, 0);
                }
            }
        }
        __syncthreads();   // staging of c+1 landed; all waves done reading buf
    }

#pragma unroll
    for (int m = 0; m < 4; ++m) {
        const long rb = (long)(tb + m * 16 + q16 * 4);
#pragma unroll
        for (int n = 0; n < 4; ++n)
#pragma unroll
            for (int r = 0; r < 4; ++r)
                atomicAdd(out + (rb + r) * E_EXP + n * 16 + r16, acc[m][n][r]);
    }
#undef STAGE
}

// ---------------- per-wave gating: softmax + top2 + scatter; returns (2nd - 3rd) gap ----
__device__ __forceinline__ void argmax64(float& v, int& i) {
#pragma unroll
    for (int s = 32; s > 0; s >>= 1) {
        float ov = __shfl_xor(v, s);
        int   oi = __shfl_xor(i, s);
        if (ov > v || (ov == v && oi < i)) { v = ov; i = oi; }   // tie-break: lower index (top_k)
    }
}

__device__ __forceinline__ float wave_gate_write(float l, int lane, float* __restrict__ outrow) {
    float v1 = l; int i1 = lane; argmax64(v1, i1);
    float v2 = (lane == i1) ? -INFINITY : l; int i2 = lane; argmax64(v2, i2);
    float v3 = (lane == i1 || lane == i2) ? -INFINITY : l; int i3 = lane; argmax64(v3, i3);
    (void)i3;

    float ex = __expf(l - v1);             // max = v1
    float Z = ex;
#pragma unroll
    for (int s = 32; s > 0; s >>= 1) Z += __shfl_xor(Z, s);

    float p1 = 1.0f / Z;                   // top-1 probability
    float p2 = __expf(v2 - v1) / Z;        // top-2 probability
    float g1 = 1.0f / (1.0f + __expf(p2 - p1));   // softmax over [p1,p2] (probs, per reference)
    float g2 = 1.0f / (1.0f + __expf(p1 - p2));

    outrow[lane] = (lane == i1) ? g1 : (lane == i2) ? g2 : 0.0f;
    return v2 - v3;
}

// ---------------- kernel 3: finalize (logits -> gating in-place) + flag risky rows ------
__global__ __launch_bounds__(256)
void finalize_router(float* __restrict__ out, const float* __restrict__ b,
                     int* __restrict__ flagc, int* __restrict__ flaglist) {
    const int lane = threadIdx.x & 63;
    const int t = blockIdx.x * 4 + (threadIdx.x >> 6);
    float l = out[(long)t * E_EXP + lane] + b[lane];
    float gap = wave_gate_write(l, lane, out + (long)t * E_EXP);
    if (gap < TAU && lane == 0) {
        int pos = atomicAdd(flagc, 1);
        flaglist[pos] = t;
    }
}

// ---------------- exact fp32 row compute (shared by fallback + no-ws path) --------------
__device__ __forceinline__ void exact_row(const float* __restrict__ x, const float* __restrict__ W,
                                          const float* __restrict__ b, float* __restrict__ out,
                                          int t, int lane, int w, float (*lds)[64]) {
    const float* xr = x + (long)t * D_DIM + w * 1024;    // broadcast across lanes (L1)
    const float* wr = W + (long)lane * D_DIM + w * 1024; // lane = expert
    float acc = 0.f;
    for (int k = 0; k < 1024; k += 4) {
        f32x4 xv = *(const f32x4*)(xr + k);
        f32x4 wv = *(const f32x4*)(wr + k);
        acc += xv[0]*wv[0] + xv[1]*wv[1] + xv[2]*wv[2] + xv[3]*wv[3];
    }
    lds[w][lane] = acc;
    __syncthreads();
    if (w == 0) {
        float l = lds[0][lane] + lds[1][lane] + lds[2][lane] + lds[3][lane] + b[lane];
        wave_gate_write(l, lane, out + (long)t * E_EXP);
    }
    __syncthreads();
}

// ---------------- kernel 4: exact fp32 recompute for flagged rows -----------------------
__global__ __launch_bounds__(256)
void fallback_exact(const float* __restrict__ x, const float* __restrict__ W,
                    const float* __restrict__ b, float* __restrict__ out,
                    const int* __restrict__ flags) {
    const int count = flags[0];
    const int lane = threadIdx.x & 63;
    const int w = threadIdx.x >> 6;
    __shared__ float lds[4][64];
    for (int fi = blockIdx.x; fi < count; fi += gridDim.x)
        exact_row(x, W, b, out, flags[1 + fi], lane, w, lds);
}

// ---------------- no-workspace safety net: exact fp32 for ALL rows ----------------------
__global__ __launch_bounds__(256)
void exact_all(const float* __restrict__ x, const float* __restrict__ W,
               const float* __restrict__ b, float* __restrict__ out) {
    const int lane = threadIdx.x & 63;
    const int w = threadIdx.x >> 6;
    __shared__ float lds[4][64];
    for (int t = blockIdx.x; t < T_TOK; t += gridDim.x)
        exact_row(x, W, b, out, t, lane, w, lds);
}

// ---------------- launch ----------------------------------------------------------------
extern "C" void kernel_launch(void* const* d_in, const int* in_sizes, int n_in,
                              void* d_out, int out_size, void* d_ws, size_t ws_size,
                              hipStream_t stream) {
    const float* x = (const float*)d_in[0];
    const float* W = (const float*)d_in[1];
    const float* b = (const float*)d_in[2];
    float* out = (float*)d_out;

    if (ws_size < (size_t)WS_NEED) {           // constant per-session -> graph-safe
        exact_all<<<2048, 256, 0, stream>>>(x, W, b, out);
        return;
    }

    char* ws = (char*)d_ws;
    short* Whi = (short*)ws;                          // 512 KiB
    short* Wlo = (short*)(ws + 512 * 1024);           // 512 KiB
    int* flagc    = (int*)(ws + 1024 * 1024);         // 4 B counter
    int* flaglist = flagc + 1;                        // up to 16384 ints (64 KiB)

    hipMemsetAsync(out, 0, (size_t)T_TOK * E_EXP * sizeof(float), stream);  // logit accumulator
    hipMemsetAsync(flagc, 0, sizeof(int), stream);

    convw_kernel<<<256, 256, 0, stream>>>(W, Whi, Wlo);
    gemm_logits<<<dim3(T_TOK / 256, KSPLIT), 256, 0, stream>>>(x, Whi, Wlo, out);
    finalize_router<<<T_TOK / 4, 256, 0, stream>>>(out, b, flagc, flaglist);
    fallback_exact<<<1024, 256, 0, stream>>>(x, W, b, out, flagc);
}